// Round 2
// baseline (1166.696 us; speedup 1.0000x reference)
//
#include <hip/hip_runtime.h>
#include <hip/hip_bf16.h>
#include <stdint.h>

// cheb_conv_withSAt: out[b,m,o,t] = relu( sum_k sum_f Theta[k,f,o] *
//                       sum_n cheb[k,n,m]*At[b,n,m]*x[b,n,f,t] )
// B=16, N=1536, F_IN=64, T=12, K=3, F_OUT=64
//
// Stage 1: y_k[b,n,o,t] = sum_f x[b,n,f,t]*Theta[k,f,o], stored bf16 as
//          Y[b][k][c=o*12+t][n]  (n contiguous -> GEMM B-operand k-contig)
// Stage 2: out[b][m][c] = sum_k sum_n W_kb[n,m] * Y[b,k,c,n],
//          W built on the fly from cheb*At, bf16 MFMA 16x16x32, 128x128 tile.

#define B_    16
#define N_    1536
#define FIN_  64
#define T_    12
#define K_    3
#define FOUT_ 64
#define C_    768   // FOUT_*T_

typedef float          f32x4 __attribute__((ext_vector_type(4)));
typedef short          s16x8 __attribute__((ext_vector_type(8)));
typedef unsigned short u16x4 __attribute__((ext_vector_type(4)));

__device__ __forceinline__ unsigned short f2bf(float f) {
    // round-half-up to bf16 (ties are measure-zero; error budget is huge)
    unsigned int u = __builtin_bit_cast(unsigned int, f);
    return (unsigned short)((u + 0x8000u) >> 16);
}

// ---------------- Stage 1: Theta transform ----------------
// grid = B*K*(N/256)*(FOUT/8) = 16*3*6*8 = 2304, block = 256
// thread owns one n (lane = n -> coalesced bf16 stores), o-chunk of 8,
// 12 t-accumulators per o => 96 fp32 acc regs.
__global__ __launch_bounds__(256) void s1_theta(const float* __restrict__ x,
                                                const float* __restrict__ Theta,
                                                unsigned short* __restrict__ Y) {
    int bid = blockIdx.x;
    int oc = bid & 7;            // FOUT/8
    int nc = (bid >> 3) % 6;     // N/256
    int k  = (bid / 48) % 3;
    int b  = bid / 144;
    int n  = nc * 256 + threadIdx.x;

    const float* xp = x + (size_t)(b * N_ + n) * (FIN_ * T_);
    const float* th = Theta + (size_t)k * FIN_ * FOUT_ + oc * 8;

    float acc[8][12];
#pragma unroll
    for (int o = 0; o < 8; ++o)
#pragma unroll
        for (int t = 0; t < 12; ++t) acc[o][t] = 0.f;

    for (int f = 0; f < FIN_; ++f) {
        f32x4 x0 = *(const f32x4*)(xp + f * 12);
        f32x4 x1 = *(const f32x4*)(xp + f * 12 + 4);
        f32x4 x2 = *(const f32x4*)(xp + f * 12 + 8);
#pragma unroll
        for (int o = 0; o < 8; ++o) {
            float w = th[f * FOUT_ + o];   // wave-uniform -> s_load
#pragma unroll
            for (int t = 0; t < 4; ++t) {
                acc[o][t]     += x0[t] * w;
                acc[o][t + 4] += x1[t] * w;
                acc[o][t + 8] += x2[t] * w;
            }
        }
    }

    unsigned short* yp = Y + (size_t)((b * K_ + k) * C_ + oc * 96) * N_ + n;
#pragma unroll
    for (int o = 0; o < 8; ++o)
#pragma unroll
        for (int t = 0; t < 12; ++t)
            yp[(size_t)(o * 12 + t) * N_] = f2bf(acc[o][t]);
}

// ---------------- Stage 2: big MFMA GEMM ----------------
// grid = B * (N/128) * (C/128) = 16*12*6 = 1152 (mt fastest), block = 256.
// LDS A: [128 m][40 bf16] (k=n contraction contiguous, stride 40 keeps
//        ds_read_b128 16B-aligned, start-bank pattern 20m mod 32 -> ~2-way)
// LDS B: [128 c][32 n] with 4-slot XOR swizzle (slot ^= c&3) on the 16B slots.
__global__ __launch_bounds__(256) void s2_gemm(const float* __restrict__ At,
                                               const float* __restrict__ cheb,
                                               const unsigned short* __restrict__ Y,
                                               float* __restrict__ out) {
    __shared__ __align__(16) unsigned short Alds[128 * 40];
    __shared__ __align__(16) unsigned short Blds[128 * 32];

    int bid = blockIdx.x;
    int mt = bid % 12;
    int ct = (bid / 12) % 6;
    int b  = bid / 72;
    int m0 = mt * 128, c0 = ct * 128;

    int tid  = threadIdx.x;
    int lane = tid & 63, wave = tid >> 6;
    int wr = (wave >> 1) * 64, wc = (wave & 1) * 64;   // wave's 64x64 sub-tile
    int l15 = lane & 15;

    // A-staging map: q = n-group (4 n), g = m-group (4 m); q fastest so a
    // wave's 64 lanes cover 8 rows x 128B contiguous global reads.
    int q = tid & 7, g = tid >> 3;

    // global staging pointers at (k=0, nt=0)
    const float* cb = cheb + (size_t)(q * 4) * N_ + (m0 + g * 4);
    const float* ab = At + (size_t)b * N_ * N_ + (size_t)(q * 4) * N_ + (m0 + g * 4);
    const unsigned short* yb = Y + (size_t)(b * K_) * (C_ * N_)
                                 + (size_t)(c0 + (tid >> 2)) * N_ + (tid & 3) * 8;

    // LDS byte offsets
    int awb = g * 320 + q * 8;                                        // A write, +i*80
    int bwb = (tid >> 2) * 64 + ((((tid & 3) ^ ((tid >> 2) & 3))) << 4); // B write (+4096 for r=1)
    int ard = (wr + l15) * 80 + (lane >> 4) * 16;                     // A frag read, +mi*1280
    int brd = (wc + l15) * 64 + (((lane >> 4) ^ (lane & 3)) << 4);    // B frag read, +ci*1024

    f32x4 acc[4][4];
#pragma unroll
    for (int mi = 0; mi < 4; ++mi)
#pragma unroll
        for (int ci = 0; ci < 4; ++ci) acc[mi][ci] = (f32x4)0.f;

    for (int nt = 0; nt < 48; ++nt) {
        for (int k = 0; k < K_; ++k) {
            // ---- global loads first (hide latency under prev MFMA/barrier)
            const float* cbk = cb + (size_t)k * (N_ * N_);
            const unsigned short* ybk = yb + (size_t)k * (C_ * N_);
            f32x4 cv[4], av[4];
#pragma unroll
            for (int j = 0; j < 4; ++j) {
                cv[j] = *(const f32x4*)(cbk + (size_t)j * N_);
                av[j] = *(const f32x4*)(ab  + (size_t)j * N_);
            }
            s16x8 y0 = *(const s16x8*)(ybk);
            s16x8 y1 = *(const s16x8*)(ybk + (size_t)64 * N_);

            __syncthreads();   // prev iter's frag reads complete

            // ---- W = cheb*At -> bf16, transposed write: Alds[m][kk]=W[n,m]
#pragma unroll
            for (int j = 0; j < 4; ++j) cv[j] *= av[j];
#pragma unroll
            for (int i = 0; i < 4; ++i) {
                u16x4 pk = { f2bf(cv[0][i]), f2bf(cv[1][i]),
                             f2bf(cv[2][i]), f2bf(cv[3][i]) };
                *(u16x4*)((char*)Alds + awb + i * 80) = pk;
            }
            *(s16x8*)((char*)Blds + bwb)        = y0;
            *(s16x8*)((char*)Blds + bwb + 4096) = y1;

            __syncthreads();   // tiles visible

            // ---- fragments + 16 MFMA
            s16x8 af[4], bv[4];
#pragma unroll
            for (int mi = 0; mi < 4; ++mi)
                af[mi] = *(const s16x8*)((const char*)Alds + ard + mi * 1280);
#pragma unroll
            for (int ci = 0; ci < 4; ++ci)
                bv[ci] = *(const s16x8*)((const char*)Blds + brd + ci * 1024);
#pragma unroll
            for (int mi = 0; mi < 4; ++mi)
#pragma unroll
                for (int ci = 0; ci < 4; ++ci)
                    acc[mi][ci] = __builtin_amdgcn_mfma_f32_16x16x32_bf16(
                        af[mi], bv[ci], acc[mi][ci], 0, 0, 0);
        }
        cb += 32 * N_;
        ab += 32 * N_;
        yb += 32;
    }

    // ---- epilogue: relu + store (D: col=lane&15, row=(lane>>4)*4+r)
    int rbase = (lane >> 4) * 4;
#pragma unroll
    for (int mi = 0; mi < 4; ++mi) {
#pragma unroll
        for (int ci = 0; ci < 4; ++ci) {
            int m = m0 + wr + mi * 16 + rbase;
            int c = c0 + wc + ci * 16 + l15;
            float* op = out + (size_t)(b * N_ + m) * C_ + c;
#pragma unroll
            for (int r = 0; r < 4; ++r) {
                float v = acc[mi][ci][r];
                op[(size_t)r * C_] = v > 0.f ? v : 0.f;
            }
        }
    }
}

extern "C" void kernel_launch(void* const* d_in, const int* in_sizes, int n_in,
                              void* d_out, int out_size, void* d_ws, size_t ws_size,
                              hipStream_t stream) {
    const float* x    = (const float*)d_in[0];
    const float* At   = (const float*)d_in[1];
    const float* cheb = (const float*)d_in[2];
    const float* Th   = (const float*)d_in[3];
    unsigned short* Y = (unsigned short*)d_ws;   // needs 16*3*768*1536*2 = 113 MB
    float* out = (float*)d_out;

    s1_theta<<<dim3(B_ * K_ * 6 * 8), dim3(256), 0, stream>>>(x, Th, Y);
    s2_gemm <<<dim3(B_ * 12 * 6),     dim3(256), 0, stream>>>(At, cheb, Y, out);
}

// Round 4
// 1037.435 us; speedup vs baseline: 1.1246x; 1.1246x over previous
//
#include <hip/hip_runtime.h>
#include <hip/hip_bf16.h>
#include <stdint.h>

// cheb_conv_withSAt: out[b,m,o,t] = relu( sum_k sum_f Theta[k,f,o] *
//                       sum_n cheb[k,n,m]*At[b,n,m]*x[b,n,f,t] )
// B=16, N=1536, F_IN=64, T=12, K=3, F_OUT=64
//
// Stage 1: y[b,k,c=(o,t),n] = sum_f x[b,n,f,t]*Theta[k,f,o]  (bf16 out)
//   - block stages 16 x-rows in LDS (coalesced), computes ALL k,o,t per read
// Stage 2: out[b][m][c] = sum_k sum_n W_kb[n,m] * Y[b,k,c,n]
//   - W=cheb*At built on the fly; bf16 MFMA 16x16x32; 128x128 tile;
//   - double-buffered LDS + distance-1 reg prefetch, 1 raw barrier / K-step

#define B_    16
#define N_    1536
#define FIN_  64
#define T_    12
#define K_    3
#define FOUT_ 64
#define C_    768   // FOUT_*T_

typedef float          f32x4 __attribute__((ext_vector_type(4)));
typedef short          s16x8 __attribute__((ext_vector_type(8)));
typedef unsigned short u16x4 __attribute__((ext_vector_type(4)));

__device__ __forceinline__ unsigned short f2bf(float f) {
    unsigned int u = __builtin_bit_cast(unsigned int, f);
    return (unsigned short)((u + 0x8000u) >> 16);
}

// ---------------- Stage 1: Theta transform ----------------
// grid = B * (N/16) = 1536, block = 256 (oo = tid>>4 in 0..15, nn = tid&15).
// LDS x tile [16][772] fp32 (stride 772 floats: 16B-aligned, bank-offset 4/row).
// Each thread: acc[3][4][12] over f=64; Theta row reads are 64B/wave, L2-hot.
__global__ __launch_bounds__(256) void s1_theta(const float* __restrict__ x,
                                                const float* __restrict__ Theta,
                                                unsigned short* __restrict__ Y) {
    __shared__ __align__(16) float xt[16][772];

    int bid = blockIdx.x;
    int nc = bid % 96, b = bid / 96;
    int n0 = nc * 16;
    int tid = threadIdx.x;

    // ---- coalesced stage: 16 rows x 768 floats = 3072 f32x4 chunks
    const float* xg = x + (size_t)(b * N_ + n0) * 768;
#pragma unroll
    for (int i = 0; i < 12; ++i) {
        int c = i * 256 + tid;
        int row = c / 192, col = (c % 192) * 4;
        f32x4 v = *(const f32x4*)(xg + (size_t)c * 4);
        *(f32x4*)&xt[row][col] = v;
    }
    __syncthreads();

    int oo = tid >> 4, nn = tid & 15;
    const float* th = Theta + oo * 4;

    float acc[3][4][12];
#pragma unroll
    for (int k = 0; k < 3; ++k)
#pragma unroll
        for (int j = 0; j < 4; ++j)
#pragma unroll
            for (int t = 0; t < 12; ++t) acc[k][j][t] = 0.f;

    for (int f = 0; f < 64; ++f) {
        f32x4 xv0 = *(const f32x4*)&xt[nn][f * 12];
        f32x4 xv1 = *(const f32x4*)&xt[nn][f * 12 + 4];
        f32x4 xv2 = *(const f32x4*)&xt[nn][f * 12 + 8];
#pragma unroll
        for (int k = 0; k < 3; ++k) {
            f32x4 tv = *(const f32x4*)(th + (size_t)(k * 64 + f) * 64);
#pragma unroll
            for (int j = 0; j < 4; ++j) {
#pragma unroll
                for (int t = 0; t < 4; ++t) {
                    acc[k][j][t]     += tv[j] * xv0[t];
                    acc[k][j][t + 4] += tv[j] * xv1[t];
                    acc[k][j][t + 8] += tv[j] * xv2[t];
                }
            }
        }
    }

    // ---- stores: lanes 0..15 (nn) write 16 consecutive bf16 -> 32B segments
    unsigned short* yp = Y + (size_t)b * (K_ * C_ * (size_t)N_) + n0 + nn;
#pragma unroll
    for (int k = 0; k < 3; ++k)
#pragma unroll
        for (int j = 0; j < 4; ++j)
#pragma unroll
            for (int t = 0; t < 12; ++t) {
                int c = (oo * 4 + j) * 12 + t;
                yp[((size_t)k * C_ + c) * N_] = f2bf(acc[k][j][t]);
            }
}

// ---------------- Stage 2: pipelined MFMA GEMM ----------------
#define NN_ ((size_t)N_ * N_)
#define CN_ ((size_t)C_ * N_)

__global__ __launch_bounds__(256, 2) void s2_gemm(const float* __restrict__ At,
                                                  const float* __restrict__ cheb,
                                                  const unsigned short* __restrict__ Y,
                                                  float* __restrict__ out) {
    __shared__ __align__(16) unsigned short Alds[2][128 * 40];
    __shared__ __align__(16) unsigned short Blds[2][128 * 32];

    // XCD-chunked bijective swizzle: 1152 = 8 * 144 exactly
    int hb = blockIdx.x;
    int lb = (hb & 7) * 144 + (hb >> 3);
    int mt = lb % 12;
    int ct = (lb / 12) % 6;
    int b  = lb / 72;
    int m0 = mt * 128, c0 = ct * 128;

    int tid  = threadIdx.x;
    int lane = tid & 63, wave = tid >> 6;
    int wr = (wave >> 1) * 64, wc = (wave & 1) * 64;
    int l15 = lane & 15;

    int q = tid & 7, g = tid >> 3;   // staging: q = n-group(4), g = m-group(4)

    const float* cb = cheb + (size_t)(q * 4) * N_ + (m0 + g * 4);
    const float* ab = At + (size_t)b * NN_ + (size_t)(q * 4) * N_ + (m0 + g * 4);
    const unsigned short* yb = Y + (size_t)(b * K_) * CN_
                                 + (size_t)(c0 + (tid >> 2)) * N_ + (tid & 3) * 8;

    int awb = g * 320 + q * 8;                                           // A write
    int bwb = (tid >> 2) * 64 + (((tid & 3) ^ ((tid >> 2) & 3)) << 4);   // B write
    int ard = (wr + l15) * 80 + (lane >> 4) * 16;                        // A read
    int brd = (wc + l15) * 64 + (((lane >> 4) ^ (lane & 3)) << 4);       // B read

    f32x4 acc[4][4];
#pragma unroll
    for (int mi = 0; mi < 4; ++mi)
#pragma unroll
        for (int ci = 0; ci < 4; ++ci) acc[mi][ci] = (f32x4)0.f;

    // prefetch slots
    f32x4 cvA[4], avA[4]; s16x8 yA0, yA1;
    f32x4 cvB[4], avB[4]; s16x8 yB0, yB1;

#define PF(CV, AV, Y0v, Y1v, DNT, KC) do {                                   \
    const float* cbk_ = cb + (size_t)(KC) * NN_ + (size_t)(DNT) * 32 * N_;   \
    const float* abk_ = ab + (size_t)(DNT) * 32 * N_;                        \
    const unsigned short* ybk_ = yb + (size_t)(KC) * CN_ + (DNT) * 32;       \
    _Pragma("unroll") for (int j = 0; j < 4; ++j) {                          \
        CV[j] = *(const f32x4*)(cbk_ + (size_t)j * N_);                      \
        AV[j] = *(const f32x4*)(abk_ + (size_t)j * N_); }                    \
    Y0v = *(const s16x8*)(ybk_);                                             \
    Y1v = *(const s16x8*)(ybk_ + (size_t)64 * N_); } while (0)

#define STEP(CV, AV, Y0v, Y1v, PCV, PAV, PY0, PY1, P, PDNT, PKC, DOPF) do {  \
    char* Ab_ = (char*)Alds[P];                                              \
    char* Bb_ = (char*)Blds[P];                                              \
    f32x4 w_[4];                                                             \
    _Pragma("unroll") for (int j = 0; j < 4; ++j) w_[j] = CV[j] * AV[j];     \
    _Pragma("unroll") for (int i = 0; i < 4; ++i) {                          \
        u16x4 pk_ = { f2bf(w_[0][i]), f2bf(w_[1][i]),                        \
                      f2bf(w_[2][i]), f2bf(w_[3][i]) };                      \
        *(u16x4*)(Ab_ + awb + i * 80) = pk_; }                               \
    *(s16x8*)(Bb_ + bwb)        = Y0v;                                       \
    *(s16x8*)(Bb_ + bwb + 4096) = Y1v;                                       \
    if (DOPF) { PF(PCV, PAV, PY0, PY1, PDNT, PKC); }                         \
    asm volatile("s_waitcnt lgkmcnt(0)" ::: "memory");                       \
    __builtin_amdgcn_s_barrier();                                            \
    __builtin_amdgcn_sched_barrier(0);                                       \
    s16x8 af_[4], bv_[4];                                                    \
    _Pragma("unroll") for (int mi = 0; mi < 4; ++mi)                         \
        af_[mi] = *(const s16x8*)((const char*)Ab_ + ard + mi * 1280);       \
    _Pragma("unroll") for (int ci = 0; ci < 4; ++ci)                         \
        bv_[ci] = *(const s16x8*)((const char*)Bb_ + brd + ci * 1024);       \
    _Pragma("unroll") for (int mi = 0; mi < 4; ++mi)                         \
        _Pragma("unroll") for (int ci = 0; ci < 4; ++ci)                     \
            acc[mi][ci] = __builtin_amdgcn_mfma_f32_16x16x32_bf16(           \
                af_[mi], bv_[ci], acc[mi][ci], 0, 0, 0);                     \
    } while (0)

    PF(cvA, avA, yA0, yA1, 0, 0);   // (nt-offset 0, k 0)

    for (int it2 = 0; it2 < 24; ++it2) {
        bool more = (it2 != 23);
        STEP(cvA, avA, yA0, yA1, cvB, avB, yB0, yB1, 0, 0, 1, true);
        STEP(cvB, avB, yB0, yB1, cvA, avA, yA0, yA1, 1, 0, 2, true);
        STEP(cvA, avA, yA0, yA1, cvB, avB, yB0, yB1, 0, 1, 0, true);
        STEP(cvB, avB, yB0, yB1, cvA, avA, yA0, yA1, 1, 1, 1, true);
        STEP(cvA, avA, yA0, yA1, cvB, avB, yB0, yB1, 0, 1, 2, true);
        STEP(cvB, avB, yB0, yB1, cvA, avA, yA0, yA1, 1, 2, 0, more);
        cb += (size_t)64 * N_;
        ab += (size_t)64 * N_;
        yb += 64;
    }
#undef PF
#undef STEP

    // ---- epilogue: relu + store (D: col=lane&15, row=(lane>>4)*4+r)
    int rbase = (lane >> 4) * 4;
#pragma unroll
    for (int mi = 0; mi < 4; ++mi) {
#pragma unroll
        for (int ci = 0; ci < 4; ++ci) {
            int m = m0 + wr + mi * 16 + rbase;
            int c = c0 + wc + ci * 16 + l15;
            float* op = out + (size_t)(b * N_ + m) * C_ + c;
#pragma unroll
            for (int r = 0; r < 4; ++r) {
                float v = acc[mi][ci][r];
                op[(size_t)r * C_] = v > 0.f ? v : 0.f;
            }
        }
    }
}

extern "C" void kernel_launch(void* const* d_in, const int* in_sizes, int n_in,
                              void* d_out, int out_size, void* d_ws, size_t ws_size,
                              hipStream_t stream) {
    const float* x    = (const float*)d_in[0];
    const float* At   = (const float*)d_in[1];
    const float* cheb = (const float*)d_in[2];
    const float* Th   = (const float*)d_in[3];
    unsigned short* Y = (unsigned short*)d_ws;   // 16*3*768*1536*2 = 113 MB
    float* out = (float*)d_out;

    s1_theta<<<dim3(B_ * 96),     dim3(256), 0, stream>>>(x, Th, Y);
    s2_gemm <<<dim3(B_ * 12 * 6), dim3(256), 0, stream>>>(At, cheb, Y, out);
}

// Round 8
// 1003.023 us; speedup vs baseline: 1.1632x; 1.0343x over previous
//
#include <hip/hip_runtime.h>
#include <hip/hip_bf16.h>
#include <stdint.h>

// cheb_conv_withSAt: out[b,m,o,t] = relu( sum_k sum_f Theta[k,f,o] *
//                       sum_n cheb[k,n,m]*At[b,n,m]*x[b,n,f,t] )
// B=16, N=1536, F_IN=64, T=12, K=3, F_OUT=64
//
// Stage 1: y[b,k,c=(o,t),n] = sum_f x[b,n,f,t]*Theta[k,f,o]  (bf16), k-outer
//          so acc is only [4][12] (48 VGPR, no spill).
// Stage 2: out[b][m][c] = sum_k sum_n W_kb[n,m] * Y[b,k,c,n]
//   m97-style: Y via global_load_lds (16B DMA, source-side XOR swizzle),
//   W=cheb*At built on the fly into A-LDS, manual dbuf, 1 barrier/K-step,
//   3 blocks/CU for implicit overlap of the barrier drain.

#define B_    16
#define N_    1536
#define FIN_  64
#define T_    12
#define K_    3
#define FOUT_ 64
#define C_    768   // FOUT_*T_
#define NN_ ((size_t)N_ * N_)
#define CN_ ((size_t)C_ * N_)

typedef float          f32x4 __attribute__((ext_vector_type(4)));
typedef short          s16x8 __attribute__((ext_vector_type(8)));
typedef unsigned short u16x4 __attribute__((ext_vector_type(4)));

__device__ __forceinline__ unsigned short f2bf(float f) {
    unsigned int u = __builtin_bit_cast(unsigned int, f);
    return (unsigned short)((u + 0x8000u) >> 16);
}

__device__ __forceinline__ void gload_lds16(const void* g, void* l) {
    __builtin_amdgcn_global_load_lds(
        (const __attribute__((address_space(1))) unsigned*)g,
        (__attribute__((address_space(3))) unsigned*)l, 16, 0, 0);
}

// ---------------- Stage 1: Theta transform ----------------
// grid = B*(N/16) = 1536, block 256 (oo = tid>>4, nn = tid&15).
// k-outer: acc[4][12] only; x tile re-read from LDS per k (cheap).
__global__ __launch_bounds__(256) void s1_theta(const float* __restrict__ x,
                                                const float* __restrict__ Theta,
                                                unsigned short* __restrict__ Y) {
    __shared__ __align__(16) float xt[16][772];

    int bid = blockIdx.x;
    int nc = bid % 96, b = bid / 96;
    int n0 = nc * 16;
    int tid = threadIdx.x;

    const float* xg = x + (size_t)(b * N_ + n0) * 768;
#pragma unroll
    for (int i = 0; i < 12; ++i) {
        int c = i * 256 + tid;
        int row = c / 192, col = (c % 192) * 4;
        *(f32x4*)&xt[row][col] = *(const f32x4*)(xg + (size_t)c * 4);
    }
    __syncthreads();

    int oo = tid >> 4, nn = tid & 15;
    unsigned short* yp = Y + (size_t)b * (K_ * CN_) + n0 + nn;

    for (int k = 0; k < 3; ++k) {
        const float* th = Theta + (size_t)k * 4096 + oo * 4;
        float acc[4][12];
#pragma unroll
        for (int j = 0; j < 4; ++j)
#pragma unroll
            for (int t = 0; t < 12; ++t) acc[j][t] = 0.f;

        for (int f = 0; f < 64; ++f) {
            f32x4 xv0 = *(const f32x4*)&xt[nn][f * 12];
            f32x4 xv1 = *(const f32x4*)&xt[nn][f * 12 + 4];
            f32x4 xv2 = *(const f32x4*)&xt[nn][f * 12 + 8];
            f32x4 tv  = *(const f32x4*)(th + (size_t)f * 64);
#pragma unroll
            for (int j = 0; j < 4; ++j) {
#pragma unroll
                for (int t = 0; t < 4; ++t) {
                    acc[j][t]     += tv[j] * xv0[t];
                    acc[j][t + 4] += tv[j] * xv1[t];
                    acc[j][t + 8] += tv[j] * xv2[t];
                }
            }
        }
#pragma unroll
        for (int j = 0; j < 4; ++j)
#pragma unroll
            for (int t = 0; t < 12; ++t) {
                int c = (oo * 4 + j) * 12 + t;
                yp[((size_t)k * C_ + c) * N_] = f2bf(acc[j][t]);
            }
    }
}

// ---------------- Stage 2: m97-style MFMA GEMM ----------------
__global__ __launch_bounds__(256, 3) void s2_gemm(const float* __restrict__ At,
                                                  const float* __restrict__ cheb,
                                                  const unsigned short* __restrict__ Y,
                                                  float* __restrict__ out) {
    __shared__ __align__(16) unsigned short Alds[2][128 * 40];
    __shared__ __align__(16) unsigned short Blds[2][128 * 32];

    // XCD-chunked bijective swizzle: 1152 = 8 * 144 exactly
    int hb = blockIdx.x;
    int lb = (hb & 7) * 144 + (hb >> 3);
    int mt = lb % 12;
    int ct = (lb / 12) % 6;
    int b  = lb / 72;
    int m0 = mt * 128, c0 = ct * 128;

    int tid  = threadIdx.x;
    int lane = tid & 63, wave = tid >> 6;
    int wr = (wave >> 1) * 64, wc = (wave & 1) * 64;
    int l15 = lane & 15;

    int q = tid & 7, g = tid >> 3;   // A staging: q = n-group(4), g = m-group(4)

    const float* cb = cheb + (size_t)(q * 4) * N_ + (m0 + g * 4);
    const float* ab = At + (size_t)b * NN_ + (size_t)(q * 4) * N_ + (m0 + g * 4);

    // Y DMA source (per-lane, source-side XOR swizzle; LDS dest linear):
    // wave w issue j covers rows (j*4+w)*16 .. +15 of the 128-row B tile.
    int lrow = lane >> 2;
    int lchunk = (lane & 3) ^ (lrow & 3);
    const unsigned short* yb = Y + (size_t)(b * K_) * CN_
                               + (size_t)(c0 + wave * 16 + lrow) * N_ + lchunk * 8;

    int awb = g * 320 + q * 8;                                       // A write byte
    int ard = (wr + l15) * 80 + (lane >> 4) * 16;                    // A frag read
    int brd = (wc + l15) * 64 + (((lane >> 4) ^ (lane & 3)) << 4);   // B frag read

    f32x4 acc[4][4];
#pragma unroll
    for (int mi = 0; mi < 4; ++mi)
#pragma unroll
        for (int ci = 0; ci < 4; ++ci) acc[mi][ci] = (f32x4)0.f;

    f32x4 cv[4], av[4];   // single prefetch slot set (distance 1)

#define PFREG(DNT, KC) do {                                                  \
    const float* cbk_ = cb + (size_t)(KC) * NN_ + (size_t)(DNT) * 32 * N_;   \
    const float* abk_ = ab + (size_t)(DNT) * 32 * N_;                        \
    _Pragma("unroll") for (int j = 0; j < 4; ++j) {                          \
        cv[j] = *(const f32x4*)(cbk_ + (size_t)j * N_);                      \
        av[j] = *(const f32x4*)(abk_ + (size_t)j * N_); } } while (0)

#define YDMA(PN, DNT, KC) do {                                               \
    const unsigned short* ys_ = yb + (size_t)(KC) * CN_ + (DNT) * 32;        \
    char* bl_ = (char*)Blds[PN] + wave * 1024;                               \
    gload_lds16(ys_, bl_);                                                   \
    gload_lds16(ys_ + (size_t)64 * N_, bl_ + 4096); } while (0)

#define WBUILD(PN) do {                                                      \
    f32x4 w_[4];                                                             \
    _Pragma("unroll") for (int j = 0; j < 4; ++j) w_[j] = cv[j] * av[j];     \
    _Pragma("unroll") for (int i = 0; i < 4; ++i) {                          \
        u16x4 pk_ = { f2bf(w_[0][i]), f2bf(w_[1][i]),                        \
                      f2bf(w_[2][i]), f2bf(w_[3][i]) };                      \
        *(u16x4*)((char*)Alds[PN] + awb + i * 80) = pk_; } } while (0)

#define STEP(P, DNTn, KCn, DNTnn, KCnn, DOSTAGE, DOLOAD) do {                \
    if (DOSTAGE) { YDMA((P) ^ 1, DNTn, KCn); WBUILD((P) ^ 1); }              \
    if (DOLOAD)  { PFREG(DNTnn, KCnn); }                                     \
    const char* Ab_ = (const char*)Alds[P];                                  \
    const char* Bb_ = (const char*)Blds[P];                                  \
    s16x8 af_[4], bv_[4];                                                    \
    _Pragma("unroll") for (int mi = 0; mi < 4; ++mi)                         \
        af_[mi] = *(const s16x8*)(Ab_ + ard + mi * 1280);                    \
    _Pragma("unroll") for (int ci = 0; ci < 4; ++ci)                         \
        bv_[ci] = *(const s16x8*)(Bb_ + brd + ci * 1024);                    \
    _Pragma("unroll") for (int mi = 0; mi < 4; ++mi)                         \
        _Pragma("unroll") for (int ci = 0; ci < 4; ++ci)                     \
            acc[mi][ci] = __builtin_amdgcn_mfma_f32_16x16x32_bf16(           \
                af_[mi], bv_[ci], acc[mi][ci], 0, 0, 0);                     \
    __syncthreads(); } while (0)

    // prologue: fill buf0 (tile 0), slots <- tile 1
    PFREG(0, 0);
    YDMA(0, 0, 0);
    WBUILD(0);
    PFREG(0, 1);
    __syncthreads();

    for (int it2 = 0; it2 < 24; ++it2) {
        bool more = (it2 != 23);
        STEP(0, 0, 1, 0, 2, true, true);
        STEP(1, 0, 2, 1, 0, true, true);
        STEP(0, 1, 0, 1, 1, true, true);
        STEP(1, 1, 1, 1, 2, true, true);
        STEP(0, 1, 2, 2, 0, true, more);
        STEP(1, 2, 0, 2, 1, more, more);
        cb += (size_t)64 * N_;
        ab += (size_t)64 * N_;
        yb += 64;
    }
#undef PFREG
#undef YDMA
#undef WBUILD
#undef STEP

    // ---- epilogue: relu + store (D: col=lane&15, row=(lane>>4)*4+r)
    int rbase = (lane >> 4) * 4;
#pragma unroll
    for (int mi = 0; mi < 4; ++mi) {
#pragma unroll
        for (int ci = 0; ci < 4; ++ci) {
            int m = m0 + wr + mi * 16 + rbase;
            int c = c0 + wc + ci * 16 + l15;
            float* op = out + (size_t)(b * N_ + m) * C_ + c;
#pragma unroll
            for (int r = 0; r < 4; ++r) {
                float v = acc[mi][ci][r];
                op[(size_t)r * C_] = v > 0.f ? v : 0.f;
            }
        }
    }
}

extern "C" void kernel_launch(void* const* d_in, const int* in_sizes, int n_in,
                              void* d_out, int out_size, void* d_ws, size_t ws_size,
                              hipStream_t stream) {
    const float* x    = (const float*)d_in[0];
    const float* At   = (const float*)d_in[1];
    const float* cheb = (const float*)d_in[2];
    const float* Th   = (const float*)d_in[3];
    unsigned short* Y = (unsigned short*)d_ws;   // 16*3*768*1536*2 = 113 MB
    float* out = (float*)d_out;

    s1_theta<<<dim3(B_ * 96),     dim3(256), 0, stream>>>(x, Th, Y);
    s2_gemm <<<dim3(B_ * 12 * 6), dim3(256), 0, stream>>>(At, cheb, Y, out);
}